// Round 3
// baseline (225263.599 us; speedup 1.0000x reference)
//
#include <hip/hip_runtime.h>
#include <math.h>

#define Bsz 64
#define Tt  1024
#define Dd  256
#define Hh  256
#define TH  512      // entities/slices < T/2, lens >= T/2 -> enc only needed for t < 512
#define G3  768

__device__ __forceinline__ float sigm(float x) { return 1.0f / (1.0f + expf(-x)); }

// Pack weights into [k4][col] float4 blocks: element (k4, col) = W[4k4+0..3][col].
// Qp/Rp: per dir [64][256] f4. Wip/Whp: per dir [64][768] f4 (from [col][k] row-major).
__global__ void pack_k(const float* __restrict__ Q, const float* __restrict__ R,
                       const float* __restrict__ Wih_f, const float* __restrict__ Whh_f,
                       const float* __restrict__ Wih_b, const float* __restrict__ Whh_b,
                       float4* __restrict__ Qp, float4* __restrict__ Rp,
                       float4* __restrict__ Wip, float4* __restrict__ Whp)
{
    int idx = blockIdx.x * 256 + threadIdx.x;
    if (idx < 32768) {                       // 2 dirs * 64 k4 * 256 cols
        int d = idx >> 14, r = idx & 16383;
        int k4 = r >> 8, j = r & 255;
        const float* S = Q + d * 65536;
        Qp[idx] = make_float4(S[(4*k4+0)*256 + j], S[(4*k4+1)*256 + j],
                              S[(4*k4+2)*256 + j], S[(4*k4+3)*256 + j]);
        S = R + d * 65536;
        Rp[idx] = make_float4(S[(4*k4+0)*256 + j], S[(4*k4+1)*256 + j],
                              S[(4*k4+2)*256 + j], S[(4*k4+3)*256 + j]);
    }
    if (idx < 98304) {                       // 2 dirs * 64 k4 * 768 cols
        int d = idx / 49152, r = idx % 49152;
        int k4 = r / 768, col = r % 768;
        const float* Wi = d ? Wih_b : Wih_f;
        const float* Wh = d ? Whh_b : Whh_f;
        Wip[idx] = *(const float4*)(Wi + col * 256 + 4 * k4);   // contiguous in source
        Whp[idx] = *(const float4*)(Wh + col * 256 + 4 * k4);
    }
}

// One WG of 512 threads per (direction, batch-pair).
// Mogrify matvecs: 8-way k-split, 4 cols/lane, weights preloaded to registers.
// GRU: 4-way k-split, 12 cols/lane, double-buffered register prefetch.
__global__ __launch_bounds__(512, 2) void scan_k(
    const int* __restrict__ sents, const int* __restrict__ lens,
    const float* __restrict__ emb,
    const float* __restrict__ bih_f, const float* __restrict__ bhh_f,
    const float* __restrict__ bih_b, const float* __restrict__ bhh_b,
    const float4* __restrict__ Qp4, const float4* __restrict__ Rp4,
    const float4* __restrict__ Wip4, const float4* __restrict__ Whp4,
    float* __restrict__ enc)
{
    const int w = blockIdx.x;                  // 0..63
    const int dir  = ((w & 7) >= 4) ? 1 : 0;   // dir constant per XCD residue class
    const int pair = (w >> 3) * 4 + (w & 3);   // 0..31, unique per dir
    const int b0 = pair * 2, b1 = b0 + 1;
    const int tid = threadIdx.x;
    const int j   = tid & 255;                 // finalize column (tid<256)
    const int ks8 = tid >> 6;                  // 0..7  k-slice for mogrify
    const int l64 = tid & 63;                  // lane col base for mogrify
    const int ks4 = tid >> 7;                  // 0..3  k-slice for GRU
    const int rE  = tid & 127;
    const int mh  = (rE >> 6) & 1;             // 0: Wih(x), 1: Whh(hm) — wave-uniform
    const int l2  = rE & 63;

    const float4* Qp  = Qp4  + dir * 16384;    // [k4][256]
    const float4* Rp  = Rp4  + dir * 16384;
    const float4* Wgp = (mh ? Whp4 : Wip4) + dir * 49152;   // this wave's GRU matrix
    const float* bih = dir ? bih_b : bih_f;
    const float* bhh = dir ? bhh_b : bhh_f;

    __shared__ __align__(16) float2 xs[256], hcs[256], hms[256];    // 6 KB
    __shared__ __align__(16) float2 redbuf[4 * 768 * 2];            // 48 KB, overlaid
    float2 (*part)[256] = (float2(*)[256])redbuf;                   // [8][256] (A-D)
    float2 (*giP)[768]  = (float2(*)[768])redbuf;                   // [4][768] (E)
    float2 (*ghP)[768]  = (float2(*)[768])(redbuf + 4 * 768);       // [4][768] (E)

    const int len0 = lens[b0], len1 = lens[b1];
    if (tid < 256) hcs[tid] = make_float2(0.f, 0.f);

    const float bi0 = bih[j], bi1 = bih[j + 256], bi2 = bih[j + 512];
    const float bh0 = bhh[j], bh1 = bhh[j + 256], bh2 = bhh[j + 512];

    int t, tstep, nsteps;
    if (!dir) { t = 0; tstep = 1; nsteps = TH; }                      // fwd: only t<512 observable
    else { int mx = max(len0, len1); t = mx - 1; tstep = -1; nsteps = mx; } // bwd: h==0 while masked

    float x0 = 0.f, x1 = 0.f, hm0 = 0.f, hm1 = 0.f;
    int tok0 = 0, tok1 = 0;
    if (tid < 256 && nsteps > 0) { tok0 = sents[b0 * Tt + t]; tok1 = sents[b1 * Tt + t]; }
    __syncthreads();

    // 8-way-k-split partial matvec: preload all 32 weight float4s, then FMA.
    auto mog_partial = [&](const float4* __restrict__ M, const float2* IN) {
        const float4* Lv = (const float4*)IN;
        const int k4b = ks8 * 8;
        const float4* Mp = M + k4b * 256 + l64;
        float4 w0[8], w1[8], w2[8], w3[8];
        #pragma unroll
        for (int i = 0; i < 8; ++i) {
            w0[i] = Mp[i * 256];
            w1[i] = Mp[i * 256 + 64];
            w2[i] = Mp[i * 256 + 128];
            w3[i] = Mp[i * 256 + 192];
        }
        float a00=0,a01=0,a10=0,a11=0,a20=0,a21=0,a30=0,a31=0;
        #pragma unroll
        for (int i = 0; i < 8; ++i) {
            const float4 v01 = Lv[2*(k4b+i)], v23 = Lv[2*(k4b+i)+1];
            a00=fmaf(w0[i].x,v01.x,a00); a00=fmaf(w0[i].y,v01.z,a00); a00=fmaf(w0[i].z,v23.x,a00); a00=fmaf(w0[i].w,v23.z,a00);
            a01=fmaf(w0[i].x,v01.y,a01); a01=fmaf(w0[i].y,v01.w,a01); a01=fmaf(w0[i].z,v23.y,a01); a01=fmaf(w0[i].w,v23.w,a01);
            a10=fmaf(w1[i].x,v01.x,a10); a10=fmaf(w1[i].y,v01.z,a10); a10=fmaf(w1[i].z,v23.x,a10); a10=fmaf(w1[i].w,v23.z,a10);
            a11=fmaf(w1[i].x,v01.y,a11); a11=fmaf(w1[i].y,v01.w,a11); a11=fmaf(w1[i].z,v23.y,a11); a11=fmaf(w1[i].w,v23.w,a11);
            a20=fmaf(w2[i].x,v01.x,a20); a20=fmaf(w2[i].y,v01.z,a20); a20=fmaf(w2[i].z,v23.x,a20); a20=fmaf(w2[i].w,v23.z,a20);
            a21=fmaf(w2[i].x,v01.y,a21); a21=fmaf(w2[i].y,v01.w,a21); a21=fmaf(w2[i].z,v23.y,a21); a21=fmaf(w2[i].w,v23.w,a21);
            a30=fmaf(w3[i].x,v01.x,a30); a30=fmaf(w3[i].y,v01.z,a30); a30=fmaf(w3[i].z,v23.x,a30); a30=fmaf(w3[i].w,v23.z,a30);
            a31=fmaf(w3[i].x,v01.y,a31); a31=fmaf(w3[i].y,v01.w,a31); a31=fmaf(w3[i].z,v23.y,a31); a31=fmaf(w3[i].w,v23.w,a31);
        }
        part[ks8][l64      ] = make_float2(a00, a01);
        part[ks8][l64 +  64] = make_float2(a10, a11);
        part[ks8][l64 + 128] = make_float2(a20, a21);
        part[ks8][l64 + 192] = make_float2(a30, a31);
    };
    auto psum = [&]() -> float2 {             // finalize-thread 8-way partial sum (col j)
        float s0 = 0.f, s1 = 0.f;
        #pragma unroll
        for (int p = 0; p < 8; ++p) { float2 v = part[p][j]; s0 += v.x; s1 += v.y; }
        return make_float2(s0, s1);
    };

    for (int s = 0; s < nsteps; ++s, t += tstep) {
        if (tid < 256) {                      // emb gather issues here, resolves under A
            x0 = emb[(size_t)tok0 * 256 + j];
            x1 = emb[(size_t)tok1 * 256 + j];
            if (s + 1 < nsteps) {             // prefetch next step's tokens
                int tn = t + tstep;
                tok0 = sents[b0 * Tt + tn];
                tok1 = sents[b1 * Tt + tn];
            }
        }
        // A: x = 2*sig(hc @ Q) * x
        mog_partial(Qp, hcs);
        __syncthreads();
        if (tid < 256) {
            float2 sv = psum();
            x0 *= 2.f * sigm(sv.x);  x1 *= 2.f * sigm(sv.y);
            xs[j] = make_float2(x0, x1);
        }
        __syncthreads();
        // B: hm = 2*sig(x @ R) * hc
        mog_partial(Rp, xs);
        __syncthreads();
        if (tid < 256) {
            float2 sv = psum();
            float2 hcj = hcs[j];
            hm0 = 2.f * sigm(sv.x) * hcj.x;  hm1 = 2.f * sigm(sv.y) * hcj.y;
            hms[j] = make_float2(hm0, hm1);
        }
        __syncthreads();
        // C: x = 2*sig(hm @ Q) * x
        mog_partial(Qp, hms);
        __syncthreads();
        if (tid < 256) {
            float2 sv = psum();
            x0 *= 2.f * sigm(sv.x);  x1 *= 2.f * sigm(sv.y);
            xs[j] = make_float2(x0, x1);
        }
        __syncthreads();
        // D: hm = 2*sig(x @ R) * hm
        mog_partial(Rp, xs);
        __syncthreads();
        if (tid < 256) {
            float2 sv = psum();
            hm0 *= 2.f * sigm(sv.x);  hm1 *= 2.f * sigm(sv.y);
            hms[j] = make_float2(hm0, hm1);
        }
        __syncthreads();
        // E: gi = x@Wih^T, gh = hm@Whh^T  (4-way k-split, 12 cols/lane, per-mat waves,
        //    double-buffered register prefetch of weights)
        {
            const float4* Lv = mh ? (const float4*)hms : (const float4*)xs;
            const int k4b = ks4 * 16;
            const float4* Wp = Wgp + (size_t)k4b * 768 + l2;
            float a[12][2];
            #pragma unroll
            for (int c = 0; c < 12; ++c) { a[c][0] = 0.f; a[c][1] = 0.f; }
            float4 wbA[12], wbB[12];
            #pragma unroll
            for (int c = 0; c < 12; ++c) wbA[c] = Wp[64 * c];          // iter 0
            #pragma unroll
            for (int ii = 0; ii < 8; ++ii) {
                const int i0 = 2 * ii, i1 = 2 * ii + 1;
                #pragma unroll
                for (int c = 0; c < 12; ++c) wbB[c] = Wp[i1 * 768 + 64 * c];   // prefetch odd
                {
                    const float4 v01 = Lv[2*(k4b+i0)], v23 = Lv[2*(k4b+i0)+1];
                    #pragma unroll
                    for (int c = 0; c < 12; ++c) {
                        a[c][0]=fmaf(wbA[c].x,v01.x,a[c][0]); a[c][0]=fmaf(wbA[c].y,v01.z,a[c][0]);
                        a[c][0]=fmaf(wbA[c].z,v23.x,a[c][0]); a[c][0]=fmaf(wbA[c].w,v23.z,a[c][0]);
                        a[c][1]=fmaf(wbA[c].x,v01.y,a[c][1]); a[c][1]=fmaf(wbA[c].y,v01.w,a[c][1]);
                        a[c][1]=fmaf(wbA[c].z,v23.y,a[c][1]); a[c][1]=fmaf(wbA[c].w,v23.w,a[c][1]);
                    }
                }
                if (ii < 7) {
                    #pragma unroll
                    for (int c = 0; c < 12; ++c) wbA[c] = Wp[(i0 + 2) * 768 + 64 * c];  // prefetch next even
                }
                {
                    const float4 v01 = Lv[2*(k4b+i1)], v23 = Lv[2*(k4b+i1)+1];
                    #pragma unroll
                    for (int c = 0; c < 12; ++c) {
                        a[c][0]=fmaf(wbB[c].x,v01.x,a[c][0]); a[c][0]=fmaf(wbB[c].y,v01.z,a[c][0]);
                        a[c][0]=fmaf(wbB[c].z,v23.x,a[c][0]); a[c][0]=fmaf(wbB[c].w,v23.z,a[c][0]);
                        a[c][1]=fmaf(wbB[c].x,v01.y,a[c][1]); a[c][1]=fmaf(wbB[c].y,v01.w,a[c][1]);
                        a[c][1]=fmaf(wbB[c].z,v23.y,a[c][1]); a[c][1]=fmaf(wbB[c].w,v23.w,a[c][1]);
                    }
                }
            }
            float2 (*dst)[768] = mh ? ghP : giP;
            #pragma unroll
            for (int c = 0; c < 12; ++c)
                dst[ks4][l2 + 64*c] = make_float2(a[c][0], a[c][1]);
        }
        __syncthreads();
        if (tid < 256) {
            float gix[3], giy[3], ghx[3], ghy[3];
            #pragma unroll
            for (int g = 0; g < 3; ++g) {
                float s0=0,s1=0,t0=0,t1=0;
                #pragma unroll
                for (int p = 0; p < 4; ++p) {
                    float2 vi = giP[p][j + 256*g]; s0 += vi.x; s1 += vi.y;
                    float2 vh = ghP[p][j + 256*g]; t0 += vh.x; t1 += vh.y;
                }
                gix[g]=s0; giy[g]=s1; ghx[g]=t0; ghy[g]=t1;
            }
            float r0 = sigm(gix[0]+bi0 + ghx[0]+bh0), r1 = sigm(giy[0]+bi0 + ghy[0]+bh0);
            float z0 = sigm(gix[1]+bi1 + ghx[1]+bh1), z1 = sigm(giy[1]+bi1 + ghy[1]+bh1);
            float n0 = tanhf(gix[2]+bi2 + r0*(ghx[2]+bh2));
            float n1 = tanhf(giy[2]+bi2 + r1*(ghy[2]+bh2));
            float u0 = (1.f - z0) * n0 + z0 * hm0;
            float u1 = (1.f - z1) * n1 + z1 * hm1;
            bool m0 = (t < len0), m1 = (t < len1);
            float2 hcj = hcs[j];
            hcs[j] = make_float2(m0 ? u0 : hcj.x, m1 ? u1 : hcj.y);
            if (t < TH) {
                atomicAdd(&enc[((size_t)b0 * TH + t) * Hh + j], m0 ? u0 : 0.f);
                atomicAdd(&enc[((size_t)b1 * TH + t) * Hh + j], m1 ? u1 : 0.f);
            }
        }
        __syncthreads();
    }
}

// One WG per batch element. Reproduces gate_attention + attention + dense exactly.
__global__ __launch_bounds__(256) void epi_k(
    const float* __restrict__ enc,
    const int* __restrict__ entities, const int* __restrict__ slices,
    const float* __restrict__ slice_lens,
    const int* __restrict__ entity_masks, const int* __restrict__ slice_masks,
    const float* __restrict__ ent_W, const float* __restrict__ ent_b,
    const float* __restrict__ att_w,
    const float* __restrict__ dense_W, const float* __restrict__ dense_b,
    float* __restrict__ out)
{
    const int b = blockIdx.x;
    const int j = threadIdx.x;
    const int wave = j >> 6, lane = j & 63;

    __shared__ float ee[8][256];
    __shared__ float p[256];
    __shared__ float rela[256];
    __shared__ float sc[264];
    __shared__ float red[4];
    __shared__ float aw[256];
    __shared__ int   spos[256];

    aw[j]   = att_w[j];
    spos[j] = slices[b * 256 + j];
    #pragma unroll
    for (int e = 0; e < 8; ++e)
        ee[e][j] = enc[((size_t)b * TH + entities[b * 8 + e]) * Hh + j];
    __syncthreads();

    float entWj = ent_W[j];
    for (int e = 0; e < 8; ++e) {
        float v = ee[e][j] * entWj;
        #pragma unroll
        for (int o = 32; o > 0; o >>= 1) v += __shfl_down(v, o);
        if (lane == 0) red[wave] = v;
        __syncthreads();
        if (j == 0) sc[e] = red[0] + red[1] + red[2] + red[3] + ent_b[0];
        __syncthreads();
    }
    float mx = -INFINITY;
    float ewv[8];
    #pragma unroll
    for (int e = 0; e < 8; ++e) {
        float v = entity_masks[b * 8 + e] ? sc[e] : -INFINITY;
        ewv[e] = v; mx = fmaxf(mx, v);
    }
    float den = 0.f;
    #pragma unroll
    for (int e = 0; e < 8; ++e) {
        ewv[e] = entity_masks[b * 8 + e] ? expf(ewv[e] - mx) : 0.f;
        den += ewv[e];
    }
    float accp = 0.f;
    #pragma unroll
    for (int e = 0; e < 8; ++e) accp += (ewv[e] / den) * ee[e][j];
    p[j] = tanhf(accp);
    __syncthreads();

    for (int s0 = wave; s0 < 256; s0 += 4) {
        const float* row = enc + ((size_t)b * TH + spos[s0]) * Hh;
        float v = 0.f;
        #pragma unroll
        for (int i = 0; i < 4; ++i) { int c = lane + 64 * i; v += row[c] * p[c]; }
        #pragma unroll
        for (int o = 32; o > 0; o >>= 1) v += __shfl_down(v, o);
        if (lane == 0) sc[s0] = v;
    }
    __syncthreads();

    float sl  = slice_lens[b];
    int   smk = slice_masks[b * 256 + j];
    float wv  = smk ? sc[j] : -INFINITY;
    float bm = wv;
    #pragma unroll
    for (int o = 32; o > 0; o >>= 1) bm = fmaxf(bm, __shfl_down(bm, o));
    __syncthreads();
    if (lane == 0) red[wave] = bm;
    __syncthreads();
    bm = fmaxf(fmaxf(red[0], red[1]), fmaxf(red[2], red[3]));
    float ex = smk ? expf(wv - bm) : 0.f;
    float sm = ex;
    #pragma unroll
    for (int o = 32; o > 0; o >>= 1) sm += __shfl_down(sm, o);
    __syncthreads();
    if (lane == 0) red[wave] = sm;
    __syncthreads();
    sm = red[0] + red[1] + red[2] + red[3];
    float ww = ex / sm * sl;
    float rl = (ww > 0.05f) ? (ww / sl) : 0.f;   // BETA = 0.05
    float rm = rl;
    #pragma unroll
    for (int o = 32; o > 0; o >>= 1) rm = fmaxf(rm, __shfl_down(rm, o));
    __syncthreads();
    if (lane == 0) red[wave] = rm;
    __syncthreads();
    rm = fmaxf(fmaxf(red[0], red[1]), fmaxf(red[2], red[3]));
    rl = rl / rm;
    rela[j] = rl;
    __syncthreads();

    for (int n = wave; n < 264; n += 4) {
        float v = 0.f;
        if (n < 8) {
            #pragma unroll
            for (int i = 0; i < 4; ++i) { int c = lane + 64 * i; v += tanhf(ee[n][c]) * aw[c]; }
        } else {
            int s0 = n - 8;
            const float* row = enc + ((size_t)b * TH + spos[s0]) * Hh;
            float rl2 = rela[s0];
            #pragma unroll
            for (int i = 0; i < 4; ++i) { int c = lane + 64 * i; v += tanhf(rl2 * row[c]) * aw[c]; }
        }
        #pragma unroll
        for (int o = 32; o > 0; o >>= 1) v += __shfl_down(v, o);
        if (lane == 0) sc[n] = v;
    }
    __syncthreads();

    float a1 = sc[j];       a1 = (a1 == 0.f) ? -INFINITY : a1;
    float a2 = (j < 8) ? sc[256 + j] : -INFINITY;
    if (a2 == 0.f) a2 = -INFINITY;
    float am = fmaxf(a1, a2);
    #pragma unroll
    for (int o = 32; o > 0; o >>= 1) am = fmaxf(am, __shfl_down(am, o));
    __syncthreads();
    if (lane == 0) red[wave] = am;
    __syncthreads();
    am = fmaxf(fmaxf(red[0], red[1]), fmaxf(red[2], red[3]));
    float e1 = (a1 == -INFINITY) ? 0.f : expf(a1 - am);
    float e2 = (a2 == -INFINITY) ? 0.f : expf(a2 - am);
    float esum = e1 + e2;
    #pragma unroll
    for (int o = 32; o > 0; o >>= 1) esum += __shfl_down(esum, o);
    __syncthreads();
    if (lane == 0) red[wave] = esum;
    __syncthreads();
    esum = red[0] + red[1] + red[2] + red[3];
    __syncthreads();
    sc[j] = e1 / esum;
    if (j < 8) sc[256 + j] = e2 / esum;
    __syncthreads();

    float att = 0.f;
    #pragma unroll
    for (int n = 0; n < 8; ++n) att += sc[n] * ee[n][j];
    for (int s0 = 0; s0 < 256; ++s0) {
        float scn = sc[8 + s0];
        if (scn > 0.f)
            att += scn * rela[s0] * enc[((size_t)b * TH + spos[s0]) * Hh + j];
    }
    float ta = tanhf(att);

    for (int l = 0; l < 19; ++l) {
        float v = ta * dense_W[l * 256 + j];
        #pragma unroll
        for (int o = 32; o > 0; o >>= 1) v += __shfl_down(v, o);
        __syncthreads();
        if (lane == 0) red[wave] = v;
        __syncthreads();
        if (j == 0) out[b * 19 + l] = red[0] + red[1] + red[2] + red[3] + dense_b[l];
    }
}

extern "C" void kernel_launch(void* const* d_in, const int* in_sizes, int n_in,
                              void* d_out, int out_size, void* d_ws, size_t ws_size,
                              hipStream_t stream) {
    (void)in_sizes; (void)n_in; (void)out_size; (void)ws_size;
    const int*   sents        = (const int*)d_in[0];
    const int*   lens         = (const int*)d_in[1];
    const int*   entities     = (const int*)d_in[2];
    const int*   slices       = (const int*)d_in[3];
    const float* slice_lens   = (const float*)d_in[4];
    const int*   entity_masks = (const int*)d_in[5];
    const int*   slice_masks  = (const int*)d_in[6];
    const float* emb          = (const float*)d_in[7];
    const float* Q            = (const float*)d_in[8];
    const float* R            = (const float*)d_in[9];
    const float* Wih_f        = (const float*)d_in[10];
    const float* Whh_f        = (const float*)d_in[11];
    const float* bih_f        = (const float*)d_in[12];
    const float* bhh_f        = (const float*)d_in[13];
    const float* Wih_b        = (const float*)d_in[14];
    const float* Whh_b        = (const float*)d_in[15];
    const float* bih_b        = (const float*)d_in[16];
    const float* bhh_b        = (const float*)d_in[17];
    const float* ent_W        = (const float*)d_in[18];
    const float* ent_b        = (const float*)d_in[19];
    const float* att_w        = (const float*)d_in[20];
    const float* dense_W      = (const float*)d_in[21];
    const float* dense_b      = (const float*)d_in[22];

    // ws layout (floats): enc [64][512][256] | Qp 32768 f4 | Rp 32768 f4 | Wip 98304 f4 | Whp 98304 f4
    float*  enc = (float*)d_ws;
    float4* Qp  = (float4*)(enc + (size_t)Bsz * TH * Hh);
    float4* Rp  = Qp + 32768;
    float4* Wip = Rp + 32768;
    float4* Whp = Wip + 98304;

    hipMemsetAsync(enc, 0, (size_t)Bsz * TH * Hh * sizeof(float), stream);
    pack_k<<<384, 256, 0, stream>>>(Q, R, Wih_f, Whh_f, Wih_b, Whh_b, Qp, Rp, Wip, Whp);
    scan_k<<<64, 512, 0, stream>>>(sents, lens, emb,
                                   bih_f, bhh_f, bih_b, bhh_b,
                                   Qp, Rp, Wip, Whp, enc);
    epi_k<<<64, 256, 0, stream>>>(enc, entities, slices, slice_lens,
                                  entity_masks, slice_masks, ent_W, ent_b,
                                  att_w, dense_W, dense_b, (float*)d_out);
}

// Round 4
// 96532.092 us; speedup vs baseline: 2.3336x; 2.3336x over previous
//
#include <hip/hip_runtime.h>
#include <math.h>

#define Bsz 64
#define Tt  1024
#define TH  512      // entities/slices < T/2, lens >= T/2 -> enc only needed for t < 512

__device__ __forceinline__ float sigm(float x) { return 1.0f / (1.0f + expf(-x)); }

// LDS float offsets (row pad 260 breaks bank conflicts; all f4-aligned)
#define WQ_OFF 0            // [8][260]  Q slice (col-local, k)
#define WR_OFF 2080         // [8][260]
#define WI_OFF 4160         // [24][260] rows = gate*8+cl
#define WH_OFF 10400        // [24][260]
#define BUF_OFF 16640       // 8 groups x 2 bufs x [4][260]
#define SMEM_FLOATS 33280   // 133120 bytes

// Weight-stationary column-parallel scan.
// 128 WGs = 2 dirs x 2 clusters x 32 slices. Each WG: 64KB weight slice in LDS.
// 8 waves/WG, wave g = independent 4-batch group pipeline (no WG-internal sync).
// Per phase: compute slice dots -> apply -> publish slice to global -> flag++;
// consumers poll flag==32*(step+1), gather full vector, continue.
__global__ __launch_bounds__(512) void scan_k(
    const int* __restrict__ sents, const int* __restrict__ lens,
    const float* __restrict__ emb,
    const float* __restrict__ Q, const float* __restrict__ R,
    const float* __restrict__ Wih_f, const float* __restrict__ Whh_f,
    const float* __restrict__ bih_f, const float* __restrict__ bhh_f,
    const float* __restrict__ Wih_b, const float* __restrict__ Whh_b,
    const float* __restrict__ bih_b, const float* __restrict__ bhh_b,
    float* __restrict__ pub, int* __restrict__ flags, float* __restrict__ enc)
{
    extern __shared__ float sm[];
    const int w = blockIdx.x;            // 0..127
    const int dir = w >> 6;              // 0 fwd, 1 bwd
    const int cluster = (w >> 5) & 1;    // 32 batches per cluster
    const int slice = w & 31;            // owns cols [8*slice, 8*slice+8)
    const int tid = threadIdx.x;

    const float* Wih = dir ? Wih_b : Wih_f;
    const float* Whh = dir ? Whh_b : Whh_f;
    const float* bih = dir ? bih_b : bih_f;
    const float* bhh = dir ? bhh_b : bhh_f;

    // ---- load weight slices to LDS (one-time) ----
    for (int i = tid; i < 2048; i += 512) {          // Q,R: [k][256] col strided
        int cl = i >> 8, k = i & 255;
        sm[WQ_OFF + cl * 260 + k] = Q[dir * 65536 + k * 256 + slice * 8 + cl];
        sm[WR_OFF + cl * 260 + k] = R[dir * 65536 + k * 256 + slice * 8 + cl];
    }
    for (int i = tid; i < 6144; i += 512) {          // Wih,Whh: rows contiguous
        int r = i >> 8, k = i & 255;
        int grow = (r >> 3) * 256 + slice * 8 + (r & 7);
        sm[WI_OFF + r * 260 + k] = Wih[grow * 256 + k];
        sm[WH_OFF + r * 260 + k] = Whh[grow * 256 + k];
    }
    __syncthreads();

    // ---- wave = group ----
    const int g    = tid >> 6;
    const int lane = tid & 63;
    const int bb   = cluster * 32 + g * 4;           // group's first batch

    const int l0 = lens[bb], l1 = lens[bb + 1], l2 = lens[bb + 2], l3 = lens[bb + 3];
    const int lenb[4] = {l0, l1, l2, l3};

    int nsteps, t0, tstep;
    if (!dir) { nsteps = TH; t0 = 0; tstep = 1; }
    else { int mx = max(max(l0, l1), max(l2, l3)); nsteps = mx; t0 = mx - 1; tstep = -1; }

    // mog mapping: lane = ks8*8 + col8 (8-way k-split, col in slice, 4 batches/lane)
    const int mcol = lane & 7, mks = lane >> 3;
    // GRU mapping: lane = ks4*16 + msel*8 + ecl
    const int eks = lane >> 4, msel = (lane >> 3) & 1, ecl = lane & 7;
    const int colg = slice * 8 + mcol;               // == slice*8+ecl for lanes<8

    // biases (lanes<8 use them)
    const float bir = bih[colg],       bhr = bhh[colg];
    const float biz = bih[256 + colg], bhz = bhh[256 + colg];
    const float bin_ = bih[512 + colg], bhn = bhh[512 + colg];

    const int cidx = ((dir * 2 + cluster) * 8 + g);
    float* pubA = pub + (size_t)(cidx * 5 + 0) * 1024;
    float* pubB = pub + (size_t)(cidx * 5 + 1) * 1024;
    float* pubC = pub + (size_t)(cidx * 5 + 2) * 1024;
    float* pubD = pub + (size_t)(cidx * 5 + 3) * 1024;
    float* pubE = pub + (size_t)(cidx * 5 + 4) * 1024;
    int* flgA = flags + (cidx * 5 + 0) * 32;
    int* flgB = flags + (cidx * 5 + 1) * 32;
    int* flgC = flags + (cidx * 5 + 2) * 32;
    int* flgD = flags + (cidx * 5 + 3) * 32;
    int* flgE = flags + (cidx * 5 + 4) * 32;

    const int BP = BUF_OFF + (g * 2 + 0) * 1040;     // [4][260]
    const int BQ = BUF_OFF + (g * 2 + 1) * 1040;

    auto poll = [&](int* f, int target) {
        while (__hip_atomic_load(f, __ATOMIC_RELAXED, __HIP_MEMORY_SCOPE_AGENT) < target)
            __builtin_amdgcn_s_sleep(1);
        (void)__hip_atomic_load(f, __ATOMIC_ACQUIRE, __HIP_MEMORY_SCOPE_AGENT);
    };
    auto post = [&](int* f) {
        if (lane == 0)
            __hip_atomic_fetch_add(f, 1, __ATOMIC_RELEASE, __HIP_MEMORY_SCOPE_AGENT);
    };
    auto gather = [&](const float* src, int dst) {   // [4][256] global -> [4][260] LDS
        int b = lane >> 4, cs = (lane & 15) * 16;
        const float4* s4 = (const float4*)(src + b * 256 + cs);
        float4 v0 = s4[0], v1 = s4[1], v2 = s4[2], v3 = s4[3];
        float* d = sm + dst + b * 260 + cs;
        *(float4*)(d) = v0; *(float4*)(d + 4) = v1;
        *(float4*)(d + 8) = v2; *(float4*)(d + 12) = v3;
    };
    auto zerobuf = [&](int dst) {
        int b = lane >> 4, cs = (lane & 15) * 16;
        float* d = sm + dst + b * 260 + cs;
        float4 z = make_float4(0.f, 0.f, 0.f, 0.f);
        *(float4*)(d) = z; *(float4*)(d + 4) = z;
        *(float4*)(d + 8) = z; *(float4*)(d + 12) = z;
    };
    auto mogdot = [&](int woff, int inoff, float* acc) {
        const float* wb = sm + woff + mcol * 260 + mks * 32;
        const float* ib = sm + inoff + mks * 32;
        acc[0] = acc[1] = acc[2] = acc[3] = 0.f;
        #pragma unroll
        for (int i = 0; i < 8; ++i) {
            float4 wv = *(const float4*)(wb + 4 * i);
            #pragma unroll
            for (int b = 0; b < 4; ++b) {
                float4 xv = *(const float4*)(ib + b * 260 + 4 * i);
                acc[b] = fmaf(wv.x, xv.x, fmaf(wv.y, xv.y,
                         fmaf(wv.z, xv.z, fmaf(wv.w, xv.w, acc[b]))));
            }
        }
        #pragma unroll
        for (int b = 0; b < 4; ++b) {
            acc[b] += __shfl_xor(acc[b], 8);
            acc[b] += __shfl_xor(acc[b], 16);
            acc[b] += __shfl_xor(acc[b], 32);
        }
    };

    float hsave[4] = {0.f, 0.f, 0.f, 0.f};
    float a[4];

    int t = t0;
    for (int s = 0; s < nsteps; ++s, t += tstep) {
        const int base = 32 * s, next = base + 32;

        // ---------- phase A: x1 = 2*sig(h @ Q) * x0 ----------
        int   tok[4];
        float x0[4];
        if (lane < 8) {
            #pragma unroll
            for (int b = 0; b < 4; ++b) tok[b] = sents[(bb + b) * Tt + t];
        }
        if (s > 0) { poll(flgE, base); gather(pubE, BP); }   // h(s-1)
        else zerobuf(BP);
        if (lane < 8) {
            #pragma unroll
            for (int b = 0; b < 4; ++b)
                x0[b] = emb[(size_t)tok[b] * 256 + colg];
        }
        mogdot(WQ_OFF, BP, a);
        if (lane < 8) {
            #pragma unroll
            for (int b = 0; b < 4; ++b) {
                float x1 = 2.f * sigm(a[b]) * x0[b];
                __builtin_nontemporal_store(x1, &pubA[b * 256 + colg]);
            }
        }
        post(flgA);

        // ---------- phase B: hm1 = 2*sig(x1 @ R) * h ----------
        poll(flgA, next); gather(pubA, BQ);
        mogdot(WR_OFF, BQ, a);
        if (lane < 8) {
            #pragma unroll
            for (int b = 0; b < 4; ++b) {
                float h_own = sm[BP + b * 260 + colg];
                hsave[b] = h_own;
                float hm1 = 2.f * sigm(a[b]) * h_own;
                __builtin_nontemporal_store(hm1, &pubB[b * 256 + colg]);
            }
        }
        post(flgB);

        // ---------- phase C: x2 = 2*sig(hm1 @ Q) * x1 ----------
        poll(flgB, next); gather(pubB, BP);                  // hm1 (h dead, saved)
        mogdot(WQ_OFF, BP, a);
        if (lane < 8) {
            #pragma unroll
            for (int b = 0; b < 4; ++b) {
                float x2 = 2.f * sigm(a[b]) * sm[BQ + b * 260 + colg];
                __builtin_nontemporal_store(x2, &pubC[b * 256 + colg]);
            }
        }
        post(flgC);

        // ---------- phase D: hm2 = 2*sig(x2 @ R) * hm1 ----------
        poll(flgC, next); gather(pubC, BQ);                  // x2 (x1 dead)
        mogdot(WR_OFF, BQ, a);
        if (lane < 8) {
            #pragma unroll
            for (int b = 0; b < 4; ++b) {
                float hm2 = 2.f * sigm(a[b]) * sm[BP + b * 260 + colg];
                __builtin_nontemporal_store(hm2, &pubD[b * 256 + colg]);
            }
        }
        post(flgD);

        // ---------- phase E: GRU ----------
        poll(flgD, next); gather(pubD, BP);                  // hm2 (hm1 dead)
        {
            const float* ib = sm + (msel ? BP : BQ) + eks * 64;  // x2 or hm2
            const float* wb = sm + (msel ? WH_OFF : WI_OFF) + ecl * 260 + eks * 64;
            float ar[4] = {0, 0, 0, 0}, az[4] = {0, 0, 0, 0}, an[4] = {0, 0, 0, 0};
            #pragma unroll
            for (int i = 0; i < 16; ++i) {
                float4 wr = *(const float4*)(wb + 4 * i);
                float4 wz = *(const float4*)(wb + 2080 + 4 * i);
                float4 wn = *(const float4*)(wb + 4160 + 4 * i);
                #pragma unroll
                for (int b = 0; b < 4; ++b) {
                    float4 xv = *(const float4*)(ib + b * 260 + 4 * i);
                    ar[b] = fmaf(wr.x, xv.x, fmaf(wr.y, xv.y, fmaf(wr.z, xv.z, fmaf(wr.w, xv.w, ar[b]))));
                    az[b] = fmaf(wz.x, xv.x, fmaf(wz.y, xv.y, fmaf(wz.z, xv.z, fmaf(wz.w, xv.w, az[b]))));
                    an[b] = fmaf(wn.x, xv.x, fmaf(wn.y, xv.y, fmaf(wn.z, xv.z, fmaf(wn.w, xv.w, an[b]))));
                }
            }
            #pragma unroll
            for (int b = 0; b < 4; ++b) {
                ar[b] += __shfl_xor(ar[b], 16); ar[b] += __shfl_xor(ar[b], 32);
                az[b] += __shfl_xor(az[b], 16); az[b] += __shfl_xor(az[b], 32);
                an[b] += __shfl_xor(an[b], 16); an[b] += __shfl_xor(an[b], 32);
            }
            float ghr[4], ghz[4], ghn[4];
            #pragma unroll
            for (int b = 0; b < 4; ++b) {
                ghr[b] = __shfl_xor(ar[b], 8);
                ghz[b] = __shfl_xor(az[b], 8);
                ghn[b] = __shfl_xor(an[b], 8);
            }
            if (lane < 8) {
                #pragma unroll
                for (int b = 0; b < 4; ++b) {
                    float r = sigm(ar[b] + bir + ghr[b] + bhr);
                    float z = sigm(az[b] + biz + ghz[b] + bhz);
                    float n = tanhf(an[b] + bin_ + r * (ghn[b] + bhn));
                    float hm2own = sm[BP + b * 260 + colg];
                    float hp = (1.f - z) * n + z * hm2own;
                    bool m = (t < lenb[b]);
                    float hnew = m ? hp : hsave[b];
                    __builtin_nontemporal_store(hnew, &pubE[b * 256 + colg]);
                    if (t < TH)
                        atomicAdd(&enc[((size_t)(bb + b) * TH + t) * 256 + colg], m ? hp : 0.f);
                }
            }
        }
        post(flgE);
    }
}

// One WG per batch element. Reproduces gate_attention + attention + dense exactly.
__global__ __launch_bounds__(256) void epi_k(
    const float* __restrict__ enc,
    const int* __restrict__ entities, const int* __restrict__ slices,
    const float* __restrict__ slice_lens,
    const int* __restrict__ entity_masks, const int* __restrict__ slice_masks,
    const float* __restrict__ ent_W, const float* __restrict__ ent_b,
    const float* __restrict__ att_w,
    const float* __restrict__ dense_W, const float* __restrict__ dense_b,
    float* __restrict__ out)
{
    const int b = blockIdx.x;
    const int j = threadIdx.x;
    const int wave = j >> 6, lane = j & 63;

    __shared__ float ee[8][256];
    __shared__ float p[256];
    __shared__ float rela[256];
    __shared__ float sc[264];
    __shared__ float red[4];
    __shared__ float aw[256];
    __shared__ int   spos[256];

    aw[j]   = att_w[j];
    spos[j] = slices[b * 256 + j];
    #pragma unroll
    for (int e = 0; e < 8; ++e)
        ee[e][j] = enc[((size_t)b * TH + entities[b * 8 + e]) * 256 + j];
    __syncthreads();

    float entWj = ent_W[j];
    for (int e = 0; e < 8; ++e) {
        float v = ee[e][j] * entWj;
        #pragma unroll
        for (int o = 32; o > 0; o >>= 1) v += __shfl_down(v, o);
        if (lane == 0) red[wave] = v;
        __syncthreads();
        if (j == 0) sc[e] = red[0] + red[1] + red[2] + red[3] + ent_b[0];
        __syncthreads();
    }
    float mx = -INFINITY;
    float ewv[8];
    #pragma unroll
    for (int e = 0; e < 8; ++e) {
        float v = entity_masks[b * 8 + e] ? sc[e] : -INFINITY;
        ewv[e] = v; mx = fmaxf(mx, v);
    }
    float den = 0.f;
    #pragma unroll
    for (int e = 0; e < 8; ++e) {
        ewv[e] = entity_masks[b * 8 + e] ? expf(ewv[e] - mx) : 0.f;
        den += ewv[e];
    }
    float accp = 0.f;
    #pragma unroll
    for (int e = 0; e < 8; ++e) accp += (ewv[e] / den) * ee[e][j];
    p[j] = tanhf(accp);
    __syncthreads();

    for (int s0 = wave; s0 < 256; s0 += 4) {
        const float* row = enc + ((size_t)b * TH + spos[s0]) * 256;
        float v = 0.f;
        #pragma unroll
        for (int i = 0; i < 4; ++i) { int c = lane + 64 * i; v += row[c] * p[c]; }
        #pragma unroll
        for (int o = 32; o > 0; o >>= 1) v += __shfl_down(v, o);
        if (lane == 0) sc[s0] = v;
    }
    __syncthreads();

    float sl  = slice_lens[b];
    int   smk = slice_masks[b * 256 + j];
    float wv  = smk ? sc[j] : -INFINITY;
    float bm = wv;
    #pragma unroll
    for (int o = 32; o > 0; o >>= 1) bm = fmaxf(bm, __shfl_down(bm, o));
    __syncthreads();
    if (lane == 0) red[wave] = bm;
    __syncthreads();
    bm = fmaxf(fmaxf(red[0], red[1]), fmaxf(red[2], red[3]));
    float ex = smk ? expf(wv - bm) : 0.f;
    float sm2 = ex;
    #pragma unroll
    for (int o = 32; o > 0; o >>= 1) sm2 += __shfl_down(sm2, o);
    __syncthreads();
    if (lane == 0) red[wave] = sm2;
    __syncthreads();
    sm2 = red[0] + red[1] + red[2] + red[3];
    float ww = ex / sm2 * sl;
    float rl = (ww > 0.05f) ? (ww / sl) : 0.f;   // BETA = 0.05
    float rm = rl;
    #pragma unroll
    for (int o = 32; o > 0; o >>= 1) rm = fmaxf(rm, __shfl_down(rm, o));
    __syncthreads();
    if (lane == 0) red[wave] = rm;
    __syncthreads();
    rm = fmaxf(fmaxf(red[0], red[1]), fmaxf(red[2], red[3]));
    rl = rl / rm;
    rela[j] = rl;
    __syncthreads();

    for (int n = wave; n < 264; n += 4) {
        float v = 0.f;
        if (n < 8) {
            #pragma unroll
            for (int i = 0; i < 4; ++i) { int c = lane + 64 * i; v += tanhf(ee[n][c]) * aw[c]; }
        } else {
            int s0 = n - 8;
            const float* row = enc + ((size_t)b * TH + spos[s0]) * 256;
            float rl2 = rela[s0];
            #pragma unroll
            for (int i = 0; i < 4; ++i) { int c = lane + 64 * i; v += tanhf(rl2 * row[c]) * aw[c]; }
        }
        #pragma unroll
        for (int o = 32; o > 0; o >>= 1) v += __shfl_down(v, o);
        if (lane == 0) sc[n] = v;
    }
    __syncthreads();

    float a1 = sc[j];       a1 = (a1 == 0.f) ? -INFINITY : a1;
    float a2 = (j < 8) ? sc[256 + j] : -INFINITY;
    if (a2 == 0.f) a2 = -INFINITY;
    float am = fmaxf(a1, a2);
    #pragma unroll
    for (int o = 32; o > 0; o >>= 1) am = fmaxf(am, __shfl_down(am, o));
    __syncthreads();
    if (lane == 0) red[wave] = am;
    __syncthreads();
    am = fmaxf(fmaxf(red[0], red[1]), fmaxf(red[2], red[3]));
    float e1 = (a1 == -INFINITY) ? 0.f : expf(a1 - am);
    float e2 = (a2 == -INFINITY) ? 0.f : expf(a2 - am);
    float esum = e1 + e2;
    #pragma unroll
    for (int o = 32; o > 0; o >>= 1) esum += __shfl_down(esum, o);
    __syncthreads();
    if (lane == 0) red[wave] = esum;
    __syncthreads();
    esum = red[0] + red[1] + red[2] + red[3];
    __syncthreads();
    sc[j] = e1 / esum;
    if (j < 8) sc[256 + j] = e2 / esum;
    __syncthreads();

    float att = 0.f;
    #pragma unroll
    for (int n = 0; n < 8; ++n) att += sc[n] * ee[n][j];
    for (int s0 = 0; s0 < 256; ++s0) {
        float scn = sc[8 + s0];
        if (scn > 0.f)
            att += scn * rela[s0] * enc[((size_t)b * TH + spos[s0]) * 256 + j];
    }
    float ta = tanhf(att);

    for (int l = 0; l < 19; ++l) {
        float v = ta * dense_W[l * 256 + j];
        #pragma unroll
        for (int o = 32; o > 0; o >>= 1) v += __shfl_down(v, o);
        __syncthreads();
        if (lane == 0) red[wave] = v;
        __syncthreads();
        if (j == 0) out[b * 19 + l] = red[0] + red[1] + red[2] + red[3] + dense_b[l];
    }
}

extern "C" void kernel_launch(void* const* d_in, const int* in_sizes, int n_in,
                              void* d_out, int out_size, void* d_ws, size_t ws_size,
                              hipStream_t stream) {
    (void)in_sizes; (void)n_in; (void)out_size; (void)ws_size;
    const int*   sents        = (const int*)d_in[0];
    const int*   lens         = (const int*)d_in[1];
    const int*   entities     = (const int*)d_in[2];
    const int*   slices       = (const int*)d_in[3];
    const float* slice_lens   = (const float*)d_in[4];
    const int*   entity_masks = (const int*)d_in[5];
    const int*   slice_masks  = (const int*)d_in[6];
    const float* emb          = (const float*)d_in[7];
    const float* Q            = (const float*)d_in[8];
    const float* R            = (const float*)d_in[9];
    const float* Wih_f        = (const float*)d_in[10];
    const float* Whh_f        = (const float*)d_in[11];
    const float* bih_f        = (const float*)d_in[12];
    const float* bhh_f        = (const float*)d_in[13];
    const float* Wih_b        = (const float*)d_in[14];
    const float* Whh_b        = (const float*)d_in[15];
    const float* bih_b        = (const float*)d_in[16];
    const float* bhh_b        = (const float*)d_in[17];
    const float* ent_W        = (const float*)d_in[18];
    const float* ent_b        = (const float*)d_in[19];
    const float* att_w        = (const float*)d_in[20];
    const float* dense_W      = (const float*)d_in[21];
    const float* dense_b      = (const float*)d_in[22];

    // ws: enc [64][512][256] f32 | pub 160x1024 f32 | flags 160x32 int
    float* enc   = (float*)d_ws;
    float* pub   = enc + (size_t)Bsz * TH * 256;
    int*   flags = (int*)(pub + 160 * 1024);

    hipFuncSetAttribute(reinterpret_cast<const void*>(scan_k),
                        hipFuncAttributeMaxDynamicSharedMemorySize,
                        SMEM_FLOATS * 4);

    hipMemsetAsync(enc, 0, (size_t)Bsz * TH * 256 * sizeof(float), stream);
    hipMemsetAsync(flags, 0, 160 * 32 * sizeof(int), stream);
    scan_k<<<128, 512, SMEM_FLOATS * 4, stream>>>(
        sents, lens, emb, Q, R,
        Wih_f, Whh_f, bih_f, bhh_f,
        Wih_b, Whh_b, bih_b, bhh_b,
        pub, flags, enc);
    epi_k<<<64, 256, 0, stream>>>(enc, entities, slices, slice_lens,
                                  entity_masks, slice_masks, ent_W, ent_b,
                                  att_w, dense_W, dense_b, (float*)d_out);
}